// Round 3
// baseline (647.153 us; speedup 1.0000x reference)
//
#include <hip/hip_runtime.h>
#include <hip/hip_bf16.h>

// GCN 2-layer: h1 = relu(GCNConv(x, W1, b1)); out = log_softmax(GCNConv(h1, W2, b2))
// GCNConv(h)[d] = dinv[d] * ( sum_{s->d} (h@W)[s]*dinv[s] + (h@W)[d]*dinv[d] ) + b
// Pre-scale rows by dinv -> fp32 atomic scatter -> epilogue applies dinv[d]+bias.
//
// Dtype story (validated rounds 0-2): float inputs are fp32, output is fp32,
// edge_index int32. Round-1 NaN = fp32 read as bf16; round-2 "stub-identical"
// absmax = correct compute but bf16 written into fp32 out buffer (half unwritten).
// Runtime detection kept as a cheap hedge for input dtypes / edge width.

#define FEAT_IN 64
#define FEAT_H  32
#define FEAT_O  16

// flags[0] = float inputs are fp32 (1) vs bf16 (0)
// flags[1] = edge_index is int64 (1) vs int32 (0)
__global__ void k_detect(const unsigned short* __restrict__ xw,
                         const int* __restrict__ ei, int* __restrict__ flags) {
    __shared__ int s_f32, s_i64nz;
    if (threadIdx.x == 0) { s_f32 = 0; s_i64nz = 0; }
    __syncthreads();
    int t = threadIdx.x;
    int hit = 0;
    for (int i = t; i < 65536; i += 256) {
        unsigned short w = xw[i];
        if ((w & 0x7F80u) == 0x7F80u) hit = 1;  // bf16 inf/nan pattern => data is fp32
    }
    if (hit) atomicOr(&s_f32, 1);
    int nz = 0;
    for (int i = t; i < 128; i += 256) {
        if (ei[2 * i + 1] != 0) nz = 1;  // int32 data: odd words are random nonzero indices
    }
    if (nz) atomicOr(&s_i64nz, 1);
    __syncthreads();
    if (t == 0) { flags[0] = s_f32; flags[1] = s_i64nz ? 0 : 1; }
}

// ---- degree ----
__global__ void k_init_deg(float* deg, int n) {
    int i = blockIdx.x * blockDim.x + threadIdx.x;
    if (i < n) deg[i] = 1.0f;  // self-loop
}

__global__ void k_count_deg(const int* __restrict__ ei, int e,
                            const int* __restrict__ flags, float* deg) {
    int i = blockIdx.x * blockDim.x + threadIdx.x;
    if (i < e) {
        int d = flags[1] ? ei[2 * (e + i)] : ei[e + i];
        atomicAdd(&deg[d], 1.0f);
    }
}

__global__ void k_rsqrt(float* deg, int n) {
    int i = blockIdx.x * blockDim.x + threadIdx.x;
    if (i < n) deg[i] = rsqrtf(deg[i]);
}

// ---- layer 1 GEMM: h1s = (x @ W1) * dinv ; acc1 init = h1s ----
// 256 threads = 8 nodes x 32 feats
__global__ void k_gemm1(const void* __restrict__ xv, const void* __restrict__ W1v,
                        const int* __restrict__ flags, const float* __restrict__ dinv,
                        float* __restrict__ h1s, float* __restrict__ acc1, int n) {
    __shared__ float sW[FEAT_IN * FEAT_H];   // 8 KB
    __shared__ float sx[8][FEAT_IN];         // 2 KB
    int t = threadIdx.x;
    bool f32 = flags[0] != 0;
    if (f32) {
        const float* W = (const float*)W1v;
        for (int i = t; i < FEAT_IN * FEAT_H; i += 256) sW[i] = W[i];
    } else {
        const __hip_bfloat16* W = (const __hip_bfloat16*)W1v;
        for (int i = t; i < FEAT_IN * FEAT_H; i += 256) sW[i] = __bfloat162float(W[i]);
    }
    int nl = t >> 5, f = t & 31;
    int node = blockIdx.x * 8 + nl;
    if (node < n) {
        float2 v;
        if (f32) {
            const float2* x2 = (const float2*)xv;
            v = x2[node * (FEAT_IN / 2) + f];
        } else {
            const __hip_bfloat162* x2 = (const __hip_bfloat162*)xv;
            v = __bfloat1622float2(x2[node * (FEAT_IN / 2) + f]);
        }
        sx[nl][2 * f]     = v.x;
        sx[nl][2 * f + 1] = v.y;
    }
    __syncthreads();
    if (node < n) {
        float acc = 0.0f;
#pragma unroll
        for (int k = 0; k < FEAT_IN; ++k) acc += sx[nl][k] * sW[k * FEAT_H + f];
        float val = acc * dinv[node];
        h1s[node * FEAT_H + f]  = val;
        acc1[node * FEAT_H + f] = val;   // self-loop term
    }
}

// ---- edge scatter, 32 feats: 256 threads = 8 edges x 32 feats ----
__global__ void k_agg32(const int* __restrict__ ei, int e, const int* __restrict__ flags,
                        const float* __restrict__ hs, float* __restrict__ acc) {
    int t = threadIdx.x;
    int el = t >> 5, f = t & 31;
    int ed = blockIdx.x * 8 + el;
    if (ed < e) {
        int s, d;
        if (flags[1]) { s = ei[2 * ed]; d = ei[2 * (e + ed)]; }
        else          { s = ei[ed];     d = ei[e + ed]; }
        atomicAdd(&acc[d * FEAT_H + f], hs[s * FEAT_H + f]);
    }
}

// ---- layer 2: z = relu(dinv*acc1 + b1); h2s = (z @ W2) * dinv; acc2 init = h2s ----
// 256 threads = 16 nodes x 16 feats
__global__ void k_layer2(const float* __restrict__ acc1, const void* __restrict__ W2v,
                         const void* __restrict__ b1v, const int* __restrict__ flags,
                         const float* __restrict__ dinv,
                         float* __restrict__ h2s, float* __restrict__ acc2, int n) {
    __shared__ float sW[FEAT_H * FEAT_O];
    __shared__ float sb1[FEAT_H];
    __shared__ float sz[16][FEAT_H + 1];
    int t = threadIdx.x;
    bool f32 = flags[0] != 0;
    if (f32) {
        const float* W = (const float*)W2v;
        for (int i = t; i < FEAT_H * FEAT_O; i += 256) sW[i] = W[i];
        if (t < FEAT_H) sb1[t] = ((const float*)b1v)[t];
    } else {
        const __hip_bfloat16* W = (const __hip_bfloat16*)W2v;
        for (int i = t; i < FEAT_H * FEAT_O; i += 256) sW[i] = __bfloat162float(W[i]);
        if (t < FEAT_H) sb1[t] = __bfloat162float(((const __hip_bfloat16*)b1v)[t]);
    }
    __syncthreads();

    int nl = t >> 4, g = t & 15;
    int node = blockIdx.x * 16 + nl;
    float dv = (node < n) ? dinv[node] : 0.0f;
    if (node < n) {
#pragma unroll
        for (int ff = 0; ff < 2; ++ff) {
            int f = g + 16 * ff;
            float z = dv * acc1[node * FEAT_H + f] + sb1[f];
            sz[nl][f] = z > 0.0f ? z : 0.0f;
        }
    }
    __syncthreads();
    if (node < n) {
        float acc = 0.0f;
#pragma unroll
        for (int f = 0; f < FEAT_H; ++f) acc += sz[nl][f] * sW[f * FEAT_O + g];
        float val = acc * dv;
        h2s[node * FEAT_O + g]  = val;
        acc2[node * FEAT_O + g] = val;   // self-loop term
    }
}

// ---- edge scatter, 16 feats: 256 threads = 16 edges x 16 feats ----
__global__ void k_agg16(const int* __restrict__ ei, int e, const int* __restrict__ flags,
                        const float* __restrict__ hs, float* __restrict__ acc) {
    int t = threadIdx.x;
    int el = t >> 4, g = t & 15;
    int ed = blockIdx.x * 16 + el;
    if (ed < e) {
        int s, d;
        if (flags[1]) { s = ei[2 * ed]; d = ei[2 * (e + ed)]; }
        else          { s = ei[ed];     d = ei[e + ed]; }
        atomicAdd(&acc[d * FEAT_O + g], hs[s * FEAT_O + g]);
    }
}

// ---- epilogue: v = dinv*acc2 + b2; out = log_softmax(v) over 16; fp32 store ----
__global__ void k_logsoftmax(const float* __restrict__ acc2, const void* __restrict__ b2v,
                             const int* __restrict__ flags, const float* __restrict__ dinv,
                             float* __restrict__ out, int n) {
    __shared__ float sb2[FEAT_O];
    int t = threadIdx.x;
    if (t < FEAT_O) {
        sb2[t] = flags[0] ? ((const float*)b2v)[t]
                          : __bfloat162float(((const __hip_bfloat16*)b2v)[t]);
    }
    __syncthreads();
    int nl = t >> 4, g = t & 15;
    int node = blockIdx.x * 16 + nl;
    if (node >= n) return;
    float v = dinv[node] * acc2[node * FEAT_O + g] + sb2[g];
    float m = v;
#pragma unroll
    for (int off = 8; off >= 1; off >>= 1) m = fmaxf(m, __shfl_xor(m, off, 16));
    float ex = __expf(v - m);
    float s = ex;
#pragma unroll
    for (int off = 8; off >= 1; off >>= 1) s += __shfl_xor(s, off, 16);
    out[node * FEAT_O + g] = v - m - logf(s);
}

extern "C" void kernel_launch(void* const* d_in, const int* in_sizes, int n_in,
                              void* d_out, int out_size, void* d_ws, size_t ws_size,
                              hipStream_t stream) {
    const void* x  = d_in[0];
    const int*  ei = (const int*)d_in[1];
    const void* W1 = d_in[2];
    const void* b1 = d_in[3];
    const void* W2 = d_in[4];
    const void* b2 = d_in[5];
    float* out = (float*)d_out;

    const int n = in_sizes[0] / FEAT_IN;   // 100000
    const int e = in_sizes[1] / 2;         // 1600000

    float* base = (float*)d_ws;
    int*   flags = (int*)base;                     // 4 ints
    float* dinv  = base + 4;                       // N
    float* acc1  = dinv + n;                       // 32N
    float* h1s   = acc1 + 32 * (size_t)n;          // 32N
    float* h2s   = h1s;                            // 16N (reuse, h1s dead after agg1)
    float* acc2  = h1s + 16 * (size_t)n;           // 16N
    // total: 65N floats + 16 B = ~26 MB

    k_detect<<<1, 256, 0, stream>>>((const unsigned short*)x, ei, flags);

    k_init_deg<<<(n + 255) / 256, 256, 0, stream>>>(dinv, n);
    k_count_deg<<<(e + 255) / 256, 256, 0, stream>>>(ei, e, flags, dinv);
    k_rsqrt<<<(n + 255) / 256, 256, 0, stream>>>(dinv, n);

    k_gemm1<<<(n + 7) / 8, 256, 0, stream>>>(x, W1, flags, dinv, h1s, acc1, n);
    k_agg32<<<(e + 7) / 8, 256, 0, stream>>>(ei, e, flags, h1s, acc1);

    k_layer2<<<(n + 15) / 16, 256, 0, stream>>>(acc1, W2, b1, flags, dinv, h2s, acc2, n);
    k_agg16<<<(e + 15) / 16, 256, 0, stream>>>(ei, e, flags, h2s, acc2);

    k_logsoftmax<<<(n + 15) / 16, 256, 0, stream>>>(acc2, b2, flags, dinv, out, n);
}

// Round 4
// 421.815 us; speedup vs baseline: 1.5342x; 1.5342x over previous
//
#include <hip/hip_runtime.h>
#include <hip/hip_bf16.h>

// GCN 2-layer: h1 = relu(GCNConv(x, W1, b1)); out = log_softmax(GCNConv(h1, W2, b2))
// GCNConv(h)[d] = dinv[d] * ( sum_{s->d} (h@W)[s]*dinv[s] + (h@W)[d]*dinv[d] ) + b
//
// Round-4 structure: build CSR (by dst) per launch, then aggregate by GATHER
// (register float4 accumulation, no float atomics). Round-3 profile showed the
// fp32 atomic scatter (k_agg32, 242 us @ 22% HBM, 9% VALU) was RMW-bound.
// Dtypes (validated r0-r3): float in/out are fp32, edge_index int32; runtime
// detection kept as hedge (flags[0]=fp32 inputs, flags[1]=int64 edges).

#define FEAT_IN 64
#define FEAT_H  32
#define FEAT_O  16

__global__ void k_detect(const unsigned short* __restrict__ xw,
                         const int* __restrict__ ei, int* __restrict__ flags) {
    __shared__ int s_f32, s_i64nz;
    if (threadIdx.x == 0) { s_f32 = 0; s_i64nz = 0; }
    __syncthreads();
    int t = threadIdx.x;
    int hit = 0;
    for (int i = t; i < 65536; i += 256) {
        unsigned short w = xw[i];
        if ((w & 0x7F80u) == 0x7F80u) hit = 1;  // bf16 inf/nan pattern => data is fp32
    }
    if (hit) atomicOr(&s_f32, 1);
    int nz = 0;
    for (int i = t; i < 128; i += 256) {
        if (ei[2 * i + 1] != 0) nz = 1;  // int32 edges: odd words random nonzero
    }
    if (nz) atomicOr(&s_i64nz, 1);
    __syncthreads();
    if (t == 0) { flags[0] = s_f32; flags[1] = s_i64nz ? 0 : 1; }
}

__global__ void k_zero(int* __restrict__ count, int n) {
    int i = blockIdx.x * blockDim.x + threadIdx.x;
    if (i < n) count[i] = 0;
}

__global__ void k_count(const int* __restrict__ ei, int e,
                        const int* __restrict__ flags, int* __restrict__ count) {
    int i = blockIdx.x * blockDim.x + threadIdx.x;
    if (i < e) {
        int d = flags[1] ? ei[2 * (e + i)] : ei[e + i];
        atomicAdd(&count[d], 1);
    }
}

// ---- exclusive scan of count[n] -> row_start[n] (3 kernels, 1024 items/block) ----
__global__ void k_scan1(const int* __restrict__ count, int* __restrict__ row_start,
                        int* __restrict__ bsum, int n) {
    __shared__ int s[256];
    int t = threadIdx.x;
    int base = blockIdx.x * 1024 + t * 4;
    int a0 = (base + 0) < n ? count[base + 0] : 0;
    int a1 = (base + 1) < n ? count[base + 1] : 0;
    int a2 = (base + 2) < n ? count[base + 2] : 0;
    int a3 = (base + 3) < n ? count[base + 3] : 0;
    int tsum = a0 + a1 + a2 + a3;
    s[t] = tsum;
    __syncthreads();
    for (int off = 1; off < 256; off <<= 1) {
        int x = (t >= off) ? s[t - off] : 0;
        __syncthreads();
        s[t] += x;
        __syncthreads();
    }
    int ex = s[t] - tsum;  // exclusive prefix of this thread's 4-chunk
    if (base + 0 < n) row_start[base + 0] = ex;
    if (base + 1 < n) row_start[base + 1] = ex + a0;
    if (base + 2 < n) row_start[base + 2] = ex + a0 + a1;
    if (base + 3 < n) row_start[base + 3] = ex + a0 + a1 + a2;
    if (t == 255) bsum[blockIdx.x] = s[255];
}

__global__ void k_scan2(int* __restrict__ bsum, int nb) {  // nb <= 256
    __shared__ int s[256];
    int t = threadIdx.x;
    int v = (t < nb) ? bsum[t] : 0;
    s[t] = v;
    __syncthreads();
    for (int off = 1; off < 256; off <<= 1) {
        int x = (t >= off) ? s[t - off] : 0;
        __syncthreads();
        s[t] += x;
        __syncthreads();
    }
    if (t < nb) bsum[t] = s[t] - v;  // exclusive block offsets
}

__global__ void k_scan3(const int* __restrict__ count, int* __restrict__ row_start,
                        int* __restrict__ cursor, float* __restrict__ dinv,
                        const int* __restrict__ bsum, int n, int e) {
    int i = blockIdx.x * blockDim.x + threadIdx.x;
    if (i < n) {
        int r = row_start[i] + bsum[i >> 10];
        row_start[i] = r;
        cursor[i] = r;
        dinv[i] = rsqrtf((float)count[i] + 1.0f);  // +1 self-loop
        if (i == 0) row_start[n] = e;
    }
}

__global__ void k_fill(const int* __restrict__ ei, int e, const int* __restrict__ flags,
                       int* __restrict__ cursor, int* __restrict__ col) {
    int i = blockIdx.x * blockDim.x + threadIdx.x;
    if (i < e) {
        int s, d;
        if (flags[1]) { s = ei[2 * i]; d = ei[2 * (e + i)]; }
        else          { s = ei[i];     d = ei[e + i]; }
        int pos = atomicAdd(&cursor[d], 1);
        col[pos] = s;
    }
}

// ---- layer 1 GEMM: h1s = (x @ W1) * dinv ; 256 thr = 8 nodes x 32 feats ----
__global__ void k_gemm1(const void* __restrict__ xv, const void* __restrict__ W1v,
                        const int* __restrict__ flags, const float* __restrict__ dinv,
                        float* __restrict__ h1s, int n) {
    __shared__ float sW[FEAT_IN * FEAT_H];
    __shared__ float sx[8][FEAT_IN];
    int t = threadIdx.x;
    bool f32 = flags[0] != 0;
    if (f32) {
        const float* W = (const float*)W1v;
        for (int i = t; i < FEAT_IN * FEAT_H; i += 256) sW[i] = W[i];
    } else {
        const __hip_bfloat16* W = (const __hip_bfloat16*)W1v;
        for (int i = t; i < FEAT_IN * FEAT_H; i += 256) sW[i] = __bfloat162float(W[i]);
    }
    int nl = t >> 5, f = t & 31;
    int node = blockIdx.x * 8 + nl;
    if (node < n) {
        float2 v;
        if (f32) {
            v = ((const float2*)xv)[node * (FEAT_IN / 2) + f];
        } else {
            v = __bfloat1622float2(((const __hip_bfloat162*)xv)[node * (FEAT_IN / 2) + f]);
        }
        sx[nl][2 * f]     = v.x;
        sx[nl][2 * f + 1] = v.y;
    }
    __syncthreads();
    if (node < n) {
        float acc = 0.0f;
#pragma unroll
        for (int k = 0; k < FEAT_IN; ++k) acc += sx[nl][k] * sW[k * FEAT_H + f];
        h1s[node * FEAT_H + f] = acc * dinv[node];
    }
}

// ---- gather layer1 (+relu+bias) fused with GEMM2: 256 thr = 32 nodes ----
// phase A: 8 lanes/node x float4 CSR gather; phase B: 32->16 GEMM from LDS.
__global__ void k_gather1_gemm2(const int* __restrict__ row_start, const int* __restrict__ col,
                                const float* __restrict__ h1s, const void* __restrict__ W2v,
                                const void* __restrict__ b1v, const int* __restrict__ flags,
                                const float* __restrict__ dinv, float* __restrict__ h2s, int n) {
    __shared__ float sW[FEAT_H * FEAT_O];
    __shared__ float sb1[FEAT_H];
    __shared__ float sz[32][FEAT_H + 1];
    int t = threadIdx.x;
    bool f32 = flags[0] != 0;
    if (f32) {
        const float* W = (const float*)W2v;
        for (int i = t; i < FEAT_H * FEAT_O; i += 256) sW[i] = W[i];
        if (t < FEAT_H) sb1[t] = ((const float*)b1v)[t];
    } else {
        const __hip_bfloat16* W = (const __hip_bfloat16*)W2v;
        for (int i = t; i < FEAT_H * FEAT_O; i += 256) sW[i] = __bfloat162float(W[i]);
        if (t < FEAT_H) sb1[t] = __bfloat162float(((const __hip_bfloat16*)b1v)[t]);
    }
    __syncthreads();

    int g = t >> 3, l = t & 7;
    int d = blockIdx.x * 32 + g;
    if (d < n) {
        const float4* h4 = (const float4*)h1s;  // h1s[s*32 + l*4] == h4[s*8 + l]
        float4 acc = h4[(size_t)d * 8 + l];     // self-loop term
        int beg = row_start[d], end = row_start[d + 1];
        for (int j = beg; j < end; ++j) {
            float4 v = h4[(size_t)col[j] * 8 + l];
            acc.x += v.x; acc.y += v.y; acc.z += v.z; acc.w += v.w;
        }
        float dv = dinv[d];
        sz[g][l * 4 + 0] = fmaxf(dv * acc.x + sb1[l * 4 + 0], 0.0f);
        sz[g][l * 4 + 1] = fmaxf(dv * acc.y + sb1[l * 4 + 1], 0.0f);
        sz[g][l * 4 + 2] = fmaxf(dv * acc.z + sb1[l * 4 + 2], 0.0f);
        sz[g][l * 4 + 3] = fmaxf(dv * acc.w + sb1[l * 4 + 3], 0.0f);
    }
    __syncthreads();
#pragma unroll
    for (int it = 0; it < 2; ++it) {
        int nl = (t >> 4) + it * 16;  // 0..31
        int o = t & 15;
        int node = blockIdx.x * 32 + nl;
        if (node < n) {
            float a = 0.0f;
#pragma unroll
            for (int f = 0; f < FEAT_H; ++f) a += sz[nl][f] * sW[f * FEAT_O + o];
            h2s[node * FEAT_O + o] = a * dinv[node];
        }
    }
}

// ---- gather layer2 fused with bias + log_softmax: 256 thr = 64 nodes x 4 lanes ----
__global__ void k_gather2_lsm(const int* __restrict__ row_start, const int* __restrict__ col,
                              const float* __restrict__ h2s, const void* __restrict__ b2v,
                              const int* __restrict__ flags, const float* __restrict__ dinv,
                              float* __restrict__ out, int n) {
    __shared__ float sb2[FEAT_O];
    int t = threadIdx.x;
    if (t < FEAT_O) {
        sb2[t] = flags[0] ? ((const float*)b2v)[t]
                          : __bfloat162float(((const __hip_bfloat16*)b2v)[t]);
    }
    __syncthreads();
    int g = t >> 2, l = t & 3;
    int d = blockIdx.x * 64 + g;
    if (d >= n) return;
    const float4* h4 = (const float4*)h2s;  // h2s[s*16 + l*4] == h4[s*4 + l]
    float4 acc = h4[(size_t)d * 4 + l];     // self-loop term
    int beg = row_start[d], end = row_start[d + 1];
    for (int j = beg; j < end; ++j) {
        float4 v = h4[(size_t)col[j] * 4 + l];
        acc.x += v.x; acc.y += v.y; acc.z += v.z; acc.w += v.w;
    }
    float dv = dinv[d];
    float v0 = dv * acc.x + sb2[l * 4 + 0];
    float v1 = dv * acc.y + sb2[l * 4 + 1];
    float v2 = dv * acc.z + sb2[l * 4 + 2];
    float v3 = dv * acc.w + sb2[l * 4 + 3];
    float m = fmaxf(fmaxf(v0, v1), fmaxf(v2, v3));
    m = fmaxf(m, __shfl_xor(m, 1, 4));
    m = fmaxf(m, __shfl_xor(m, 2, 4));
    float ssum = __expf(v0 - m) + __expf(v1 - m) + __expf(v2 - m) + __expf(v3 - m);
    ssum += __shfl_xor(ssum, 1, 4);
    ssum += __shfl_xor(ssum, 2, 4);
    float lg = m + logf(ssum);
    float4 o4 = { v0 - lg, v1 - lg, v2 - lg, v3 - lg };
    ((float4*)out)[(size_t)d * 4 + l] = o4;
}

extern "C" void kernel_launch(void* const* d_in, const int* in_sizes, int n_in,
                              void* d_out, int out_size, void* d_ws, size_t ws_size,
                              hipStream_t stream) {
    const void* x  = d_in[0];
    const int*  ei = (const int*)d_in[1];
    const void* W1 = d_in[2];
    const void* b1 = d_in[3];
    const void* W2 = d_in[4];
    const void* b2 = d_in[5];
    float* out = (float*)d_out;

    const int n = in_sizes[0] / FEAT_IN;   // 100000
    const int e = in_sizes[1] / 2;         // 1600000

    // workspace layout (float4-aligned arrays first)
    float* h1s  = (float*)d_ws;                 // 32n
    float* h2s  = h1s + 32 * (size_t)n;         // 16n
    float* dinv = h2s + 16 * (size_t)n;         // n
    int* flags     = (int*)(dinv + n);          // 4
    int* count     = flags + 4;                 // n
    int* row_start = count + n;                 // n+1
    int* cursor    = row_start + n + 1;         // n
    int* bsum      = cursor + n;                // 1024
    int* col       = bsum + 1024;               // e
    // total ~= 49n floats + (3n + e + ~1k) ints ~= 27.2 MB

    const int nb = (n + 1023) / 1024;  // scan blocks (98)

    k_detect<<<1, 256, 0, stream>>>((const unsigned short*)x, ei, flags);

    k_zero <<<(n + 255) / 256, 256, 0, stream>>>(count, n);
    k_count<<<(e + 255) / 256, 256, 0, stream>>>(ei, e, flags, count);
    k_scan1<<<nb, 256, 0, stream>>>(count, row_start, bsum, n);
    k_scan2<<<1, 256, 0, stream>>>(bsum, nb);
    k_scan3<<<(n + 255) / 256, 256, 0, stream>>>(count, row_start, cursor, dinv, bsum, n, e);
    k_fill <<<(e + 255) / 256, 256, 0, stream>>>(ei, e, flags, cursor, col);

    k_gemm1<<<(n + 7) / 8, 256, 0, stream>>>(x, W1, flags, dinv, h1s, n);
    k_gather1_gemm2<<<(n + 31) / 32, 256, 0, stream>>>(row_start, col, h1s, W2, b1, flags,
                                                       dinv, h2s, n);
    k_gather2_lsm<<<(n + 63) / 64, 256, 0, stream>>>(row_start, col, h2s, b2, flags,
                                                     dinv, out, n);
}

// Round 5
// 232.996 us; speedup vs baseline: 2.7775x; 1.8104x over previous
//
#include <hip/hip_runtime.h>
#include <hip/hip_bf16.h>

// GCN 2-layer: h1 = relu(GCNConv(x, W1, b1)); out = log_softmax(GCNConv(h1, W2, b2))
// GCNConv(h)[d] = dinv[d] * ( sum_{s->d} (h@W)[s]*dinv[s] + (h@W)[d]*dinv[d] ) + b
//
// Round-5: bucketed CSR build. Round-4 profile: k_fill 140us with WRITE_SIZE
// 105MB for a 6.4MB col array (64B line churn per 4B scattered write across
// XCDs). Fix: radix-partition edges by dst>>8 into 391 buckets (block-private
// write runs), then per-bucket block builds row_start/dinv/col entirely from
// LDS (kills k_zero/k_count/node-scan too). Aggregation stays gather-based.
// Dtypes (validated r0-r4): fp32 in/out, int32 edges; runtime flags kept as hedge.

#define FEAT_IN 64
#define FEAT_H  32
#define FEAT_O  16
#define MAXNB   512   // max buckets (n <= 131072)
#define PART_G  192   // partition blocks

__global__ void k_detect(const uint4* __restrict__ xw4,
                         const int* __restrict__ ei, int* __restrict__ flags) {
    __shared__ int s_f32, s_i64nz;
    if (threadIdx.x == 0) { s_f32 = 0; s_i64nz = 0; }
    __syncthreads();
    int t = threadIdx.x;
    int hit = 0;
    for (int i = t; i < 4096; i += 256) {  // first 32768 halfwords of x
        uint4 u = xw4[i];
        unsigned a0 = u.x, a1 = u.y, a2 = u.z, a3 = u.w;
        if ((a0 & 0x7F800000u) == 0x7F800000u || (a0 & 0x00007F80u) == 0x00007F80u) hit = 1;
        if ((a1 & 0x7F800000u) == 0x7F800000u || (a1 & 0x00007F80u) == 0x00007F80u) hit = 1;
        if ((a2 & 0x7F800000u) == 0x7F800000u || (a2 & 0x00007F80u) == 0x00007F80u) hit = 1;
        if ((a3 & 0x7F800000u) == 0x7F800000u || (a3 & 0x00007F80u) == 0x00007F80u) hit = 1;
    }
    if (hit) atomicOr(&s_f32, 1);
    int nz = 0;
    for (int i = t; i < 128; i += 256) {
        if (ei[2 * i + 1] != 0) nz = 1;  // int32 edges: odd words random nonzero
    }
    if (nz) atomicOr(&s_i64nz, 1);
    __syncthreads();
    if (t == 0) { flags[0] = s_f32; flags[1] = s_i64nz ? 0 : 1; }
}

// ---- pass 1: per-block bucket histogram -> hist[b*G + g] ----
__global__ void k_hist(const int* __restrict__ ei, int e, const int* __restrict__ flags,
                       int* __restrict__ hist, int G, int NBk) {
    __shared__ int lh[MAXNB];
    int t = threadIdx.x, g = blockIdx.x;
    for (int i = t; i < NBk; i += 256) lh[i] = 0;
    __syncthreads();
    int chunk = (e + G - 1) / G;
    int beg = g * chunk, end = min(e, beg + chunk);
    bool i64 = flags[1] != 0;
    for (int i = beg + t; i < end; i += 256) {
        int d = i64 ? ei[2 * (e + i)] : ei[e + i];
        atomicAdd(&lh[d >> 8], 1);
    }
    __syncthreads();
    for (int i = t; i < NBk; i += 256) hist[(size_t)i * G + g] = lh[i];
}

// ---- generic 3-kernel exclusive scan (len <= 256*1024) ----
__global__ void k_scan1(const int* __restrict__ in, int* __restrict__ out,
                        int* __restrict__ bsum, int len) {
    __shared__ int s[256];
    int t = threadIdx.x;
    int base = blockIdx.x * 1024 + t * 4;
    int a0 = (base + 0) < len ? in[base + 0] : 0;
    int a1 = (base + 1) < len ? in[base + 1] : 0;
    int a2 = (base + 2) < len ? in[base + 2] : 0;
    int a3 = (base + 3) < len ? in[base + 3] : 0;
    int tsum = a0 + a1 + a2 + a3;
    s[t] = tsum;
    __syncthreads();
    for (int off = 1; off < 256; off <<= 1) {
        int x = (t >= off) ? s[t - off] : 0;
        __syncthreads();
        s[t] += x;
        __syncthreads();
    }
    int ex = s[t] - tsum;
    if (base + 0 < len) out[base + 0] = ex;
    if (base + 1 < len) out[base + 1] = ex + a0;
    if (base + 2 < len) out[base + 2] = ex + a0 + a1;
    if (base + 3 < len) out[base + 3] = ex + a0 + a1 + a2;
    if (t == 255) bsum[blockIdx.x] = s[255];
}

__global__ void k_scan2(int* __restrict__ bsum, int nb) {  // nb <= 256
    __shared__ int s[256];
    int t = threadIdx.x;
    int v = (t < nb) ? bsum[t] : 0;
    s[t] = v;
    __syncthreads();
    for (int off = 1; off < 256; off <<= 1) {
        int x = (t >= off) ? s[t - off] : 0;
        __syncthreads();
        s[t] += x;
        __syncthreads();
    }
    if (t < nb) bsum[t] = s[t] - v;
}

__global__ void k_scan_add(int* __restrict__ out, const int* __restrict__ bsum, int len) {
    int i = blockIdx.x * blockDim.x + threadIdx.x;
    if (i < len) out[i] += bsum[i >> 10];
}

// ---- pass 2: scatter (s,d) records into bucket-ordered part[], block-private runs ----
__global__ void k_partition(const int* __restrict__ ei, int e, const int* __restrict__ flags,
                            const int* __restrict__ base, int2* __restrict__ part,
                            int G, int NBk) {
    __shared__ int cur[MAXNB];
    int t = threadIdx.x, g = blockIdx.x;
    for (int i = t; i < NBk; i += 256) cur[i] = base[(size_t)i * G + g];
    __syncthreads();
    int chunk = (e + G - 1) / G;
    int beg = g * chunk, end = min(e, beg + chunk);
    bool i64 = flags[1] != 0;
    for (int i = beg + t; i < end; i += 256) {
        int s, d;
        if (i64) { s = ei[2 * i]; d = ei[2 * (e + i)]; }
        else     { s = ei[i];     d = ei[e + i]; }
        int pos = atomicAdd(&cur[d >> 8], 1);
        part[pos] = make_int2(s, d);
    }
}

// ---- pass 3: per-bucket CSR: LDS count -> scan -> row_start/dinv -> col fill ----
__global__ void k_bucket_csr(const int2* __restrict__ part, const int* __restrict__ base,
                             int e, int G, int NBk, int n,
                             int* __restrict__ row_start, int* __restrict__ col,
                             float* __restrict__ dinv) {
    __shared__ int cnt[256], spre[256], cur[256], ssc[256];
    int t = threadIdx.x, b = blockIdx.x;
    int beg = base[(size_t)b * G];
    int end = (b == NBk - 1) ? e : base[(size_t)(b + 1) * G];
    cnt[t] = 0; cur[t] = 0;
    __syncthreads();
    for (int j = beg + t; j < end; j += 256) atomicAdd(&cnt[part[j].y & 255], 1);
    __syncthreads();
    int v = cnt[t];
    ssc[t] = v;
    __syncthreads();
    for (int off = 1; off < 256; off <<= 1) {
        int x = (t >= off) ? ssc[t - off] : 0;
        __syncthreads();
        ssc[t] += x;
        __syncthreads();
    }
    spre[t] = ssc[t] - v;  // exclusive prefix within bucket
    int node = b * 256 + t;
    if (node < n) {
        row_start[node] = beg + spre[t];
        dinv[node] = rsqrtf((float)v + 1.0f);  // +1 self-loop
    }
    if (b == NBk - 1 && t == 0) row_start[n] = e;
    __syncthreads();
    for (int j = beg + t; j < end; j += 256) {
        int2 r = part[j];
        int dl = r.y & 255;
        int off = atomicAdd(&cur[dl], 1);
        col[beg + spre[dl] + off] = r.x;
    }
}

// ---- layer 1 GEMM: h1s = (x @ W1) * dinv ; 256 thr = 8 nodes x 32 feats ----
__global__ void k_gemm1(const void* __restrict__ xv, const void* __restrict__ W1v,
                        const int* __restrict__ flags, const float* __restrict__ dinv,
                        float* __restrict__ h1s, int n) {
    __shared__ float sW[FEAT_IN * FEAT_H];
    __shared__ float sx[8][FEAT_IN];
    int t = threadIdx.x;
    bool f32 = flags[0] != 0;
    if (f32) {
        const float* W = (const float*)W1v;
        for (int i = t; i < FEAT_IN * FEAT_H; i += 256) sW[i] = W[i];
    } else {
        const __hip_bfloat16* W = (const __hip_bfloat16*)W1v;
        for (int i = t; i < FEAT_IN * FEAT_H; i += 256) sW[i] = __bfloat162float(W[i]);
    }
    int nl = t >> 5, f = t & 31;
    int node = blockIdx.x * 8 + nl;
    if (node < n) {
        float2 v;
        if (f32) {
            v = ((const float2*)xv)[node * (FEAT_IN / 2) + f];
        } else {
            v = __bfloat1622float2(((const __hip_bfloat162*)xv)[node * (FEAT_IN / 2) + f]);
        }
        sx[nl][2 * f]     = v.x;
        sx[nl][2 * f + 1] = v.y;
    }
    __syncthreads();
    if (node < n) {
        float acc = 0.0f;
#pragma unroll
        for (int k = 0; k < FEAT_IN; ++k) acc += sx[nl][k] * sW[k * FEAT_H + f];
        h1s[node * FEAT_H + f] = acc * dinv[node];
    }
}

// ---- gather layer1 (+relu+bias) fused with GEMM2: 256 thr = 32 nodes ----
__global__ void k_gather1_gemm2(const int* __restrict__ row_start, const int* __restrict__ col,
                                const float* __restrict__ h1s, const void* __restrict__ W2v,
                                const void* __restrict__ b1v, const int* __restrict__ flags,
                                const float* __restrict__ dinv, float* __restrict__ h2s, int n) {
    __shared__ float sW[FEAT_H * FEAT_O];
    __shared__ float sb1[FEAT_H];
    __shared__ float sz[32][FEAT_H + 1];
    int t = threadIdx.x;
    bool f32 = flags[0] != 0;
    if (f32) {
        const float* W = (const float*)W2v;
        for (int i = t; i < FEAT_H * FEAT_O; i += 256) sW[i] = W[i];
        if (t < FEAT_H) sb1[t] = ((const float*)b1v)[t];
    } else {
        const __hip_bfloat16* W = (const __hip_bfloat16*)W2v;
        for (int i = t; i < FEAT_H * FEAT_O; i += 256) sW[i] = __bfloat162float(W[i]);
        if (t < FEAT_H) sb1[t] = __bfloat162float(((const __hip_bfloat16*)b1v)[t]);
    }
    __syncthreads();

    int g = t >> 3, l = t & 7;
    int d = blockIdx.x * 32 + g;
    if (d < n) {
        const float4* h4 = (const float4*)h1s;  // h1s[s*32 + l*4] == h4[s*8 + l]
        float4 acc = h4[(size_t)d * 8 + l];     // self-loop term
        int beg = row_start[d], end = row_start[d + 1];
        for (int j = beg; j < end; ++j) {
            float4 v = h4[(size_t)col[j] * 8 + l];
            acc.x += v.x; acc.y += v.y; acc.z += v.z; acc.w += v.w;
        }
        float dv = dinv[d];
        sz[g][l * 4 + 0] = fmaxf(dv * acc.x + sb1[l * 4 + 0], 0.0f);
        sz[g][l * 4 + 1] = fmaxf(dv * acc.y + sb1[l * 4 + 1], 0.0f);
        sz[g][l * 4 + 2] = fmaxf(dv * acc.z + sb1[l * 4 + 2], 0.0f);
        sz[g][l * 4 + 3] = fmaxf(dv * acc.w + sb1[l * 4 + 3], 0.0f);
    }
    __syncthreads();
#pragma unroll
    for (int it = 0; it < 2; ++it) {
        int nl = (t >> 4) + it * 16;  // 0..31
        int o = t & 15;
        int node = blockIdx.x * 32 + nl;
        if (node < n) {
            float a = 0.0f;
#pragma unroll
            for (int f = 0; f < FEAT_H; ++f) a += sz[nl][f] * sW[f * FEAT_O + o];
            h2s[node * FEAT_O + o] = a * dinv[node];
        }
    }
}

// ---- gather layer2 fused with bias + log_softmax: 256 thr = 64 nodes x 4 lanes ----
__global__ void k_gather2_lsm(const int* __restrict__ row_start, const int* __restrict__ col,
                              const float* __restrict__ h2s, const void* __restrict__ b2v,
                              const int* __restrict__ flags, const float* __restrict__ dinv,
                              float* __restrict__ out, int n) {
    __shared__ float sb2[FEAT_O];
    int t = threadIdx.x;
    if (t < FEAT_O) {
        sb2[t] = flags[0] ? ((const float*)b2v)[t]
                          : __bfloat162float(((const __hip_bfloat16*)b2v)[t]);
    }
    __syncthreads();
    int g = t >> 2, l = t & 3;
    int d = blockIdx.x * 64 + g;
    if (d >= n) return;
    const float4* h4 = (const float4*)h2s;  // h2s[s*16 + l*4] == h4[s*4 + l]
    float4 acc = h4[(size_t)d * 4 + l];     // self-loop term
    int beg = row_start[d], end = row_start[d + 1];
    for (int j = beg; j < end; ++j) {
        float4 v = h4[(size_t)col[j] * 4 + l];
        acc.x += v.x; acc.y += v.y; acc.z += v.z; acc.w += v.w;
    }
    float dv = dinv[d];
    float v0 = dv * acc.x + sb2[l * 4 + 0];
    float v1 = dv * acc.y + sb2[l * 4 + 1];
    float v2 = dv * acc.z + sb2[l * 4 + 2];
    float v3 = dv * acc.w + sb2[l * 4 + 3];
    float m = fmaxf(fmaxf(v0, v1), fmaxf(v2, v3));
    m = fmaxf(m, __shfl_xor(m, 1, 4));
    m = fmaxf(m, __shfl_xor(m, 2, 4));
    float ssum = __expf(v0 - m) + __expf(v1 - m) + __expf(v2 - m) + __expf(v3 - m);
    ssum += __shfl_xor(ssum, 1, 4);
    ssum += __shfl_xor(ssum, 2, 4);
    float lg = m + logf(ssum);
    float4 o4 = { v0 - lg, v1 - lg, v2 - lg, v3 - lg };
    ((float4*)out)[(size_t)d * 4 + l] = o4;
}

extern "C" void kernel_launch(void* const* d_in, const int* in_sizes, int n_in,
                              void* d_out, int out_size, void* d_ws, size_t ws_size,
                              hipStream_t stream) {
    const void* x  = d_in[0];
    const int*  ei = (const int*)d_in[1];
    const void* W1 = d_in[2];
    const void* b1 = d_in[3];
    const void* W2 = d_in[4];
    const void* b2 = d_in[5];
    float* out = (float*)d_out;

    const int n = in_sizes[0] / FEAT_IN;   // 100000
    const int e = in_sizes[1] / 2;         // 1600000
    const int NBk = (n + 255) >> 8;        // 391 buckets
    const int G = PART_G;                  // 192 partition blocks
    const int hlen = NBk * G;              // 75072

    // workspace layout; part (int2 e = 8e bytes) aliased by h1s (32n floats = 8e bytes,
    // written only after k_bucket_csr has consumed part)
    int2*  part = (int2*)d_ws;                       // e int2  (12.8 MB)
    float* h1s  = (float*)d_ws;                      // 32n floats, same region
    float* h2s  = (float*)d_ws + 32 * (size_t)n;     // 16n
    float* dinv = h2s + 16 * (size_t)n;              // n
    int* flags     = (int*)(dinv + n);               // 4
    int* hist      = flags + 4;                      // hlen
    int* base      = hist + hlen;                    // hlen
    int* bsum      = base + hlen;                    // 256
    int* row_start = bsum + 256;                     // n+1
    int* col       = row_start + n + 1;              // e
    // total ~= 49n floats + (2*hlen + n + e + ~300) ints ~= 27 MB

    k_detect<<<1, 256, 0, stream>>>((const uint4*)x, ei, flags);

    k_hist<<<G, 256, 0, stream>>>(ei, e, flags, hist, G, NBk);
    int snb = (hlen + 1023) / 1024;  // 74
    k_scan1<<<snb, 256, 0, stream>>>(hist, base, bsum, hlen);
    k_scan2<<<1, 256, 0, stream>>>(bsum, snb);
    k_scan_add<<<(hlen + 255) / 256, 256, 0, stream>>>(base, bsum, hlen);
    k_partition<<<G, 256, 0, stream>>>(ei, e, flags, base, part, G, NBk);
    k_bucket_csr<<<NBk, 256, 0, stream>>>(part, base, e, G, NBk, n, row_start, col, dinv);

    k_gemm1<<<(n + 7) / 8, 256, 0, stream>>>(x, W1, flags, dinv, h1s, n);
    k_gather1_gemm2<<<(n + 31) / 32, 256, 0, stream>>>(row_start, col, h1s, W2, b1, flags,
                                                       dinv, h2s, n);
    k_gather2_lsm<<<(n + 63) / 64, 256, 0, stream>>>(row_start, col, h2s, b2, flags,
                                                     dinv, out, n);
}

// Round 6
// 213.978 us; speedup vs baseline: 3.0244x; 1.0889x over previous
//
#include <hip/hip_runtime.h>
#include <hip/hip_bf16.h>

// GCN 2-layer: h1 = relu(GCNConv(x, W1, b1)); out = log_softmax(GCNConv(h1, W2, b2))
// GCNConv(h)[d] = dinv[d] * ( sum_{s->d} (h@W)[s]*dinv[s] + (h@W)[d]*dinv[d] ) + b
//
// Round-6: r5 profile showed k_gather1_gemm2 (47us) latency-bound: VALUBusy 13%,
// 24% HBM-side, 0 conflicts -- one dependent float4 gather in flight per node
// group. Fix: unroll CSR gather x4 (4 independent float4 loads in flight).
// Also: partition record packed to 4B (src|dlow<<24), scan_add folded into
// consumers. Dtypes (validated r0-r5): fp32 in/out, int32 edges; flags = hedge.

#define FEAT_IN 64
#define FEAT_H  32
#define FEAT_O  16
#define MAXNB   512   // max buckets (n <= 131072; also need n < 2^24 for packing)
#define PART_G  192   // partition blocks

__global__ void k_detect(const uint4* __restrict__ xw4,
                         const int* __restrict__ ei, int* __restrict__ flags) {
    __shared__ int s_f32, s_i64nz;
    if (threadIdx.x == 0) { s_f32 = 0; s_i64nz = 0; }
    __syncthreads();
    int t = threadIdx.x;
    int hit = 0;
    for (int i = t; i < 4096; i += 256) {
        uint4 u = xw4[i];
        unsigned a0 = u.x, a1 = u.y, a2 = u.z, a3 = u.w;
        if ((a0 & 0x7F800000u) == 0x7F800000u || (a0 & 0x00007F80u) == 0x00007F80u) hit = 1;
        if ((a1 & 0x7F800000u) == 0x7F800000u || (a1 & 0x00007F80u) == 0x00007F80u) hit = 1;
        if ((a2 & 0x7F800000u) == 0x7F800000u || (a2 & 0x00007F80u) == 0x00007F80u) hit = 1;
        if ((a3 & 0x7F800000u) == 0x7F800000u || (a3 & 0x00007F80u) == 0x00007F80u) hit = 1;
    }
    if (hit) atomicOr(&s_f32, 1);
    int nz = 0;
    for (int i = t; i < 128; i += 256) {
        if (ei[2 * i + 1] != 0) nz = 1;  // int32 edges: odd words random nonzero
    }
    if (nz) atomicOr(&s_i64nz, 1);
    __syncthreads();
    if (t == 0) { flags[0] = s_f32; flags[1] = s_i64nz ? 0 : 1; }
}

// ---- pass 1: per-block bucket histogram -> hist[b*G + g] ----
__global__ void k_hist(const int* __restrict__ ei, int e, const int* __restrict__ flags,
                       int* __restrict__ hist, int G, int NBk) {
    __shared__ int lh[MAXNB];
    int t = threadIdx.x, g = blockIdx.x;
    for (int i = t; i < NBk; i += 256) lh[i] = 0;
    __syncthreads();
    int chunk = (e + G - 1) / G;
    int beg = g * chunk, end = min(e, beg + chunk);
    bool i64 = flags[1] != 0;
    for (int i = beg + t; i < end; i += 256) {
        int d = i64 ? ei[2 * (e + i)] : ei[e + i];
        atomicAdd(&lh[d >> 8], 1);
    }
    __syncthreads();
    for (int i = t; i < NBk; i += 256) hist[(size_t)i * G + g] = lh[i];
}

// ---- generic 3-kernel exclusive scan (len <= 256*1024); final = out[i]+bsum[i>>10] ----
__global__ void k_scan1(const int* __restrict__ in, int* __restrict__ out,
                        int* __restrict__ bsum, int len) {
    __shared__ int s[256];
    int t = threadIdx.x;
    int base = blockIdx.x * 1024 + t * 4;
    int a0 = (base + 0) < len ? in[base + 0] : 0;
    int a1 = (base + 1) < len ? in[base + 1] : 0;
    int a2 = (base + 2) < len ? in[base + 2] : 0;
    int a3 = (base + 3) < len ? in[base + 3] : 0;
    int tsum = a0 + a1 + a2 + a3;
    s[t] = tsum;
    __syncthreads();
    for (int off = 1; off < 256; off <<= 1) {
        int x = (t >= off) ? s[t - off] : 0;
        __syncthreads();
        s[t] += x;
        __syncthreads();
    }
    int ex = s[t] - tsum;
    if (base + 0 < len) out[base + 0] = ex;
    if (base + 1 < len) out[base + 1] = ex + a0;
    if (base + 2 < len) out[base + 2] = ex + a0 + a1;
    if (base + 3 < len) out[base + 3] = ex + a0 + a1 + a2;
    if (t == 255) bsum[blockIdx.x] = s[255];
}

__global__ void k_scan2(int* __restrict__ bsum, int nb) {  // nb <= 256
    __shared__ int s[256];
    int t = threadIdx.x;
    int v = (t < nb) ? bsum[t] : 0;
    s[t] = v;
    __syncthreads();
    for (int off = 1; off < 256; off <<= 1) {
        int x = (t >= off) ? s[t - off] : 0;
        __syncthreads();
        s[t] += x;
        __syncthreads();
    }
    if (t < nb) bsum[t] = s[t] - v;
}

__device__ __forceinline__ int base_at(const int* base, const int* bsum, int idx) {
    return base[idx] + bsum[idx >> 10];
}

// ---- pass 2: scatter packed (src | dlow<<24) into bucket-ordered part[] ----
__global__ void k_partition(const int* __restrict__ ei, int e, const int* __restrict__ flags,
                            const int* __restrict__ base, const int* __restrict__ bsum,
                            int* __restrict__ part, int G, int NBk) {
    __shared__ int cur[MAXNB];
    int t = threadIdx.x, g = blockIdx.x;
    for (int i = t; i < NBk; i += 256) cur[i] = base_at(base, bsum, i * G + g);
    __syncthreads();
    int chunk = (e + G - 1) / G;
    int beg = g * chunk, end = min(e, beg + chunk);
    bool i64 = flags[1] != 0;
    for (int i = beg + t; i < end; i += 256) {
        int s, d;
        if (i64) { s = ei[2 * i]; d = ei[2 * (e + i)]; }
        else     { s = ei[i];     d = ei[e + i]; }
        int pos = atomicAdd(&cur[d >> 8], 1);
        part[pos] = s | ((d & 255) << 24);   // n < 2^24
    }
}

// ---- pass 3: per-bucket CSR: LDS count -> scan -> row_start/dinv -> col fill ----
__global__ void k_bucket_csr(const int* __restrict__ part, const int* __restrict__ base,
                             const int* __restrict__ bsum, int e, int G, int NBk, int n,
                             int* __restrict__ row_start, int* __restrict__ col,
                             float* __restrict__ dinv) {
    __shared__ int cnt[256], spre[256], cur[256], ssc[256];
    int t = threadIdx.x, b = blockIdx.x;
    int beg = base_at(base, bsum, b * G);
    int end = (b == NBk - 1) ? e : base_at(base, bsum, (b + 1) * G);
    cnt[t] = 0; cur[t] = 0;
    __syncthreads();
    for (int j = beg + t; j < end; j += 256) atomicAdd(&cnt[((unsigned)part[j]) >> 24], 1);
    __syncthreads();
    int v = cnt[t];
    ssc[t] = v;
    __syncthreads();
    for (int off = 1; off < 256; off <<= 1) {
        int x = (t >= off) ? ssc[t - off] : 0;
        __syncthreads();
        ssc[t] += x;
        __syncthreads();
    }
    spre[t] = ssc[t] - v;  // exclusive prefix within bucket
    int node = b * 256 + t;
    if (node < n) {
        row_start[node] = beg + spre[t];
        dinv[node] = rsqrtf((float)v + 1.0f);  // +1 self-loop
    }
    if (b == NBk - 1 && t == 0) row_start[n] = e;
    __syncthreads();
    for (int j = beg + t; j < end; j += 256) {
        int r = part[j];
        int dl = ((unsigned)r) >> 24;
        int off = atomicAdd(&cur[dl], 1);
        col[beg + spre[dl] + off] = r & 0x00FFFFFF;
    }
}

// ---- layer 1 GEMM: h1s = (x @ W1) * dinv ; 256 thr = 8 nodes x 32 feats ----
__global__ void k_gemm1(const void* __restrict__ xv, const void* __restrict__ W1v,
                        const int* __restrict__ flags, const float* __restrict__ dinv,
                        float* __restrict__ h1s, int n) {
    __shared__ float sW[FEAT_IN * FEAT_H];
    __shared__ float sx[8][FEAT_IN];
    int t = threadIdx.x;
    bool f32 = flags[0] != 0;
    if (f32) {
        const float* W = (const float*)W1v;
        for (int i = t; i < FEAT_IN * FEAT_H; i += 256) sW[i] = W[i];
    } else {
        const __hip_bfloat16* W = (const __hip_bfloat16*)W1v;
        for (int i = t; i < FEAT_IN * FEAT_H; i += 256) sW[i] = __bfloat162float(W[i]);
    }
    int nl = t >> 5, f = t & 31;
    int node = blockIdx.x * 8 + nl;
    if (node < n) {
        float2 v;
        if (f32) {
            v = ((const float2*)xv)[node * (FEAT_IN / 2) + f];
        } else {
            v = __bfloat1622float2(((const __hip_bfloat162*)xv)[node * (FEAT_IN / 2) + f]);
        }
        sx[nl][2 * f]     = v.x;
        sx[nl][2 * f + 1] = v.y;
    }
    __syncthreads();
    if (node < n) {
        float acc = 0.0f;
#pragma unroll
        for (int k = 0; k < FEAT_IN; ++k) acc += sx[nl][k] * sW[k * FEAT_H + f];
        h1s[node * FEAT_H + f] = acc * dinv[node];
    }
}

// ---- gather layer1 (+relu+bias) fused with GEMM2: 256 thr = 32 nodes x 8 lanes ----
__global__ void k_gather1_gemm2(const int* __restrict__ row_start, const int* __restrict__ col,
                                const float* __restrict__ h1s, const void* __restrict__ W2v,
                                const void* __restrict__ b1v, const int* __restrict__ flags,
                                const float* __restrict__ dinv, float* __restrict__ h2s, int n) {
    __shared__ float sW[FEAT_H * FEAT_O];
    __shared__ float sb1[FEAT_H];
    __shared__ float sz[32][FEAT_H + 1];
    int t = threadIdx.x;
    bool f32 = flags[0] != 0;
    if (f32) {
        const float* W = (const float*)W2v;
        for (int i = t; i < FEAT_H * FEAT_O; i += 256) sW[i] = W[i];
        if (t < FEAT_H) sb1[t] = ((const float*)b1v)[t];
    } else {
        const __hip_bfloat16* W = (const __hip_bfloat16*)W2v;
        for (int i = t; i < FEAT_H * FEAT_O; i += 256) sW[i] = __bfloat162float(W[i]);
        if (t < FEAT_H) sb1[t] = __bfloat162float(((const __hip_bfloat16*)b1v)[t]);
    }
    __syncthreads();

    int g = t >> 3, l = t & 7;
    int d = blockIdx.x * 32 + g;
    if (d < n) {
        const float4* h4 = (const float4*)h1s;  // h1s[s*32 + l*4] == h4[s*8 + l]
        float4 acc = h4[(size_t)d * 8 + l];     // self-loop term
        int beg = row_start[d], end = row_start[d + 1];
        int j = beg;
        for (; j + 4 <= end; j += 4) {          // 4 independent gathers in flight
            int c0 = col[j + 0], c1 = col[j + 1], c2 = col[j + 2], c3 = col[j + 3];
            float4 v0 = h4[(size_t)c0 * 8 + l];
            float4 v1 = h4[(size_t)c1 * 8 + l];
            float4 v2 = h4[(size_t)c2 * 8 + l];
            float4 v3 = h4[(size_t)c3 * 8 + l];
            acc.x += (v0.x + v1.x) + (v2.x + v3.x);
            acc.y += (v0.y + v1.y) + (v2.y + v3.y);
            acc.z += (v0.z + v1.z) + (v2.z + v3.z);
            acc.w += (v0.w + v1.w) + (v2.w + v3.w);
        }
        for (; j < end; ++j) {
            float4 v = h4[(size_t)col[j] * 8 + l];
            acc.x += v.x; acc.y += v.y; acc.z += v.z; acc.w += v.w;
        }
        float dv = dinv[d];
        sz[g][l * 4 + 0] = fmaxf(dv * acc.x + sb1[l * 4 + 0], 0.0f);
        sz[g][l * 4 + 1] = fmaxf(dv * acc.y + sb1[l * 4 + 1], 0.0f);
        sz[g][l * 4 + 2] = fmaxf(dv * acc.z + sb1[l * 4 + 2], 0.0f);
        sz[g][l * 4 + 3] = fmaxf(dv * acc.w + sb1[l * 4 + 3], 0.0f);
    }
    __syncthreads();
#pragma unroll
    for (int it = 0; it < 2; ++it) {
        int nl = (t >> 4) + it * 16;  // 0..31
        int o = t & 15;
        int node = blockIdx.x * 32 + nl;
        if (node < n) {
            float a = 0.0f;
#pragma unroll
            for (int f = 0; f < FEAT_H; ++f) a += sz[nl][f] * sW[f * FEAT_O + o];
            h2s[node * FEAT_O + o] = a * dinv[node];
        }
    }
}

// ---- gather layer2 fused with bias + log_softmax: 256 thr = 64 nodes x 4 lanes ----
__global__ void k_gather2_lsm(const int* __restrict__ row_start, const int* __restrict__ col,
                              const float* __restrict__ h2s, const void* __restrict__ b2v,
                              const int* __restrict__ flags, const float* __restrict__ dinv,
                              float* __restrict__ out, int n) {
    __shared__ float sb2[FEAT_O];
    int t = threadIdx.x;
    if (t < FEAT_O) {
        sb2[t] = flags[0] ? ((const float*)b2v)[t]
                          : __bfloat162float(((const __hip_bfloat16*)b2v)[t]);
    }
    __syncthreads();
    int g = t >> 2, l = t & 3;
    int d = blockIdx.x * 64 + g;
    if (d >= n) return;
    const float4* h4 = (const float4*)h2s;  // h2s[s*16 + l*4] == h4[s*4 + l]
    float4 acc = h4[(size_t)d * 4 + l];     // self-loop term
    int beg = row_start[d], end = row_start[d + 1];
    int j = beg;
    for (; j + 4 <= end; j += 4) {
        int c0 = col[j + 0], c1 = col[j + 1], c2 = col[j + 2], c3 = col[j + 3];
        float4 v0 = h4[(size_t)c0 * 4 + l];
        float4 v1 = h4[(size_t)c1 * 4 + l];
        float4 v2 = h4[(size_t)c2 * 4 + l];
        float4 v3 = h4[(size_t)c3 * 4 + l];
        acc.x += (v0.x + v1.x) + (v2.x + v3.x);
        acc.y += (v0.y + v1.y) + (v2.y + v3.y);
        acc.z += (v0.z + v1.z) + (v2.z + v3.z);
        acc.w += (v0.w + v1.w) + (v2.w + v3.w);
    }
    for (; j < end; ++j) {
        float4 v = h4[(size_t)col[j] * 4 + l];
        acc.x += v.x; acc.y += v.y; acc.z += v.z; acc.w += v.w;
    }
    float dv = dinv[d];
    float v0 = dv * acc.x + sb2[l * 4 + 0];
    float v1 = dv * acc.y + sb2[l * 4 + 1];
    float v2 = dv * acc.z + sb2[l * 4 + 2];
    float v3 = dv * acc.w + sb2[l * 4 + 3];
    float m = fmaxf(fmaxf(v0, v1), fmaxf(v2, v3));
    m = fmaxf(m, __shfl_xor(m, 1, 4));
    m = fmaxf(m, __shfl_xor(m, 2, 4));
    float ssum = __expf(v0 - m) + __expf(v1 - m) + __expf(v2 - m) + __expf(v3 - m);
    ssum += __shfl_xor(ssum, 1, 4);
    ssum += __shfl_xor(ssum, 2, 4);
    float lg = m + logf(ssum);
    float4 o4 = { v0 - lg, v1 - lg, v2 - lg, v3 - lg };
    ((float4*)out)[(size_t)d * 4 + l] = o4;
}

extern "C" void kernel_launch(void* const* d_in, const int* in_sizes, int n_in,
                              void* d_out, int out_size, void* d_ws, size_t ws_size,
                              hipStream_t stream) {
    const void* x  = d_in[0];
    const int*  ei = (const int*)d_in[1];
    const void* W1 = d_in[2];
    const void* b1 = d_in[3];
    const void* W2 = d_in[4];
    const void* b2 = d_in[5];
    float* out = (float*)d_out;

    const int n = in_sizes[0] / FEAT_IN;   // 100000
    const int e = in_sizes[1] / 2;         // 1600000
    const int NBk = (n + 255) >> 8;        // 391 buckets
    const int G = PART_G;                  // 192 partition blocks
    const int hlen = NBk * G;              // 75072

    // workspace; part (4B*e = 6.4MB) aliased with h1s (32n fp = 12.8MB; written
    // only after k_bucket_csr consumed part)
    int*   part = (int*)d_ws;                        // e ints
    float* h1s  = (float*)d_ws;                      // 32n floats, same region
    float* h2s  = (float*)d_ws + 32 * (size_t)n;     // 16n
    float* dinv = h2s + 16 * (size_t)n;              // n
    int* flags     = (int*)(dinv + n);               // 4
    int* hist      = flags + 4;                      // hlen
    int* base      = hist + hlen;                    // hlen
    int* bsum      = base + hlen;                    // 256
    int* row_start = bsum + 256;                     // n+1
    int* col       = row_start + n + 1;              // e

    k_detect<<<1, 256, 0, stream>>>((const uint4*)x, ei, flags);

    k_hist<<<G, 256, 0, stream>>>(ei, e, flags, hist, G, NBk);
    int snb = (hlen + 1023) / 1024;  // 74
    k_scan1<<<snb, 256, 0, stream>>>(hist, base, bsum, hlen);
    k_scan2<<<1, 256, 0, stream>>>(bsum, snb);
    k_partition<<<G, 256, 0, stream>>>(ei, e, flags, base, bsum, part, G, NBk);
    k_bucket_csr<<<NBk, 256, 0, stream>>>(part, base, bsum, e, G, NBk, n,
                                          row_start, col, dinv);

    k_gemm1<<<(n + 7) / 8, 256, 0, stream>>>(x, W1, flags, dinv, h1s, n);
    k_gather1_gemm2<<<(n + 31) / 32, 256, 0, stream>>>(row_start, col, h1s, W2, b1, flags,
                                                       dinv, h2s, n);
    k_gather2_lsm<<<(n + 63) / 64, 256, 0, stream>>>(row_start, col, h2s, b2, flags,
                                                     dinv, out, n);
}